// Round 1
// baseline (275.393 us; speedup 1.0000x reference)
//
#include <hip/hip_runtime.h>

#define S_LEN 4096
#define DHEAD 64
#define BQ    128      // Q rows per block (4 waves x 32)
#define BK    64       // K/V rows per tile
#define NT    (S_LEN / BK)
#define KPAD  72       // halfs; 144 B row stride (16B-aligned) -- P scratch only
#define NBH   16
#define TILE_HALFS (BK * DHEAD)   // 4096 halfs = 8 KB per tile image
#define WS_KV_HALFS ((size_t)NBH * NT * TILE_HALFS)

typedef __fp16   pk16x2 __attribute__((ext_vector_type(2)));  // cvt_pkrtz result
typedef _Float16 half4v __attribute__((ext_vector_type(4)));
typedef _Float16 half8  __attribute__((ext_vector_type(8)));
typedef float    f32x4  __attribute__((ext_vector_type(4)));

// async global->LDS, 16B per lane; LDS dest is wave-uniform base + lane*16
__device__ __forceinline__ void gl_lds16(const _Float16* g, _Float16* l) {
    __builtin_amdgcn_global_load_lds(
        (const __attribute__((address_space(1))) unsigned int*)g,
        (__attribute__((address_space(3))) unsigned int*)l, 16, 0, 0);
}

// ---------------------------------------------------------------------------
// Pass 1 (fallback path only): is the mask anywhere nonzero?
// ---------------------------------------------------------------------------
__global__ void mask_flag_kernel(const float4* __restrict__ mask, int* __restrict__ flag) {
    const long stride = 2048L * 256;
    long i = (long)blockIdx.x * 256 + threadIdx.x;
    int nz = 0;
    #pragma unroll
    for (int it = 0; it < 8; ++it) {
        float4 a = mask[i + it * stride];
        nz |= (a.x != 0.f) | (a.y != 0.f) | (a.z != 0.f) | (a.w != 0.f);
    }
    if (__any(nz)) {
        if ((threadIdx.x & 63) == 0) atomicOr(flag, 1);
    }
}

// ---------------------------------------------------------------------------
// Pass 1 (workspace path): convert K/V fp32 -> fp16 tile images in the exact
// swizzled LDS layout the attention kernel wants, AND scan the mask.
//   wsK tile image: [r][16B-chunk c] = K[r][8*(c ^ (r&7)) .. +8]   (row-major)
//   wsV tile image: [d][16B-chunk c] = V[8*(c ^ (d&7)) .. +8][d]   (transposed)
// grid = (1024, 3): y==0 K-tiles, y==1 V-tiles, y==2 mask scan.
// ---------------------------------------------------------------------------
__global__ void conv_kernel(const float* __restrict__ Kg, const float* __restrict__ Vg,
                            const float* __restrict__ mask,
                            _Float16* __restrict__ wsK, _Float16* __restrict__ wsV,
                            int* __restrict__ flag) {
    const int tid  = threadIdx.x;
    const int tile = blockIdx.x;                // 0..1023 = bh*64 + kt
    __shared__ __align__(16) _Float16 T[64][64];

    if (blockIdx.y == 0) {
        // ---- K: within-row 16B chunk permutation, rows stay row-major ----
        const float* Ksrc = Kg + (long)tile * TILE_HALFS;   // 4096 floats/tile
        _Float16*    dst  = wsK + (long)tile * TILE_HALFS;
        #pragma unroll
        for (int it = 0; it < 2; ++it) {
            int m = tid + it * 256;             // out chunk id 0..511
            int r = m >> 3, c = m & 7;
            const float4* s4 = (const float4*)(Ksrc + r * DHEAD + ((c ^ (r & 7)) << 3));
            float4 a = s4[0], b = s4[1];
            union { pk16x2 p[4]; half8 h; } u;
            u.p[0] = __builtin_amdgcn_cvt_pkrtz(a.x, a.y);
            u.p[1] = __builtin_amdgcn_cvt_pkrtz(a.z, a.w);
            u.p[2] = __builtin_amdgcn_cvt_pkrtz(b.x, b.y);
            u.p[3] = __builtin_amdgcn_cvt_pkrtz(b.z, b.w);
            *(half8*)(dst + m * 8) = u.h;
        }
    } else if (blockIdx.y == 1) {
        // ---- V: transpose 64x64 tile via LDS, then swizzled chunk writeout ----
        const float* Vsrc = Vg + (long)tile * TILE_HALFS;
        const int r  = tid >> 2;
        const int d0 = (tid & 3) << 4;
        const float4* s4 = (const float4*)(Vsrc + r * DHEAD + d0);
        float vv[16];
        *(float4*)&vv[0]  = s4[0];
        *(float4*)&vv[4]  = s4[1];
        *(float4*)&vv[8]  = s4[2];
        *(float4*)&vv[12] = s4[3];
        #pragma unroll
        for (int j = 0; j < 16; j += 2) {
            pk16x2 p = __builtin_amdgcn_cvt_pkrtz(vv[j], vv[j + 1]);
            T[d0 + j][r]     = *((_Float16*)&p);
            T[d0 + j + 1][r] = *((_Float16*)&p + 1);
        }
        __syncthreads();
        _Float16* dst = wsV + (long)tile * TILE_HALFS;
        #pragma unroll
        for (int it = 0; it < 2; ++it) {
            int m = tid + it * 256;
            int d = m >> 3, c = m & 7;
            *(half8*)(dst + m * 8) = *(const half8*)&T[d][(c ^ (d & 7)) << 3];
        }
    } else {
        // ---- mask scan: 1024 blocks x 256 threads x 16 float4 = 64 MB ----
        const float4* m4 = (const float4*)mask;
        const long stride = 1024L * 256;
        long i = (long)blockIdx.x * 256 + tid;
        int nz = 0;
        #pragma unroll
        for (int it = 0; it < 16; ++it) {
            float4 a = m4[i + it * stride];
            nz |= (a.x != 0.f) | (a.y != 0.f) | (a.z != 0.f) | (a.w != 0.f);
        }
        if (__any(nz)) {
            if ((tid & 63) == 0) atomicOr(flag, 1);
        }
    }
}

// ---------------------------------------------------------------------------
// Pass 2 (workspace path): flash attention. K/V staged straight from fp16
// tile images via global_load_lds (no cvt, no ds_write, no staging VGPRs).
// XOR-swizzled rows -> conflict-free ds_read_b128. Exact defer-rescale.
// ---------------------------------------------------------------------------
__global__ __launch_bounds__(256, 2) void attn_ws_kernel(
    const float* __restrict__ Q, const _Float16* __restrict__ KW,
    const _Float16* __restrict__ VW, const int* __restrict__ dk,
    const float* __restrict__ mask, const int* __restrict__ maskflag,
    float* __restrict__ O)
{
    const int qt   = blockIdx.x;      // 0..31
    const int bh   = blockIdx.y;      // 0..15
    const int tid  = threadIdx.x;
    const int wave = tid >> 6;
    const int lane = tid & 63;
    const int l15  = lane & 15;
    const int quad = lane >> 4;
    const int sw   = (l15 & 7) << 3;  // row-XOR swizzle (halfs); rows 16-periodic
    const int rq8  = quad << 3;

    const long base = (long)bh * S_LEN * DHEAD;
    const float* Qh = Q + base;
    float*       Oh = O + base;
    const _Float16* gk = KW + (long)bh * (NT * TILE_HALFS);
    const _Float16* gv = VW + (long)bh * (NT * TILE_HALFS);

    const int q0 = qt * BQ + wave * 32;            // this wave's 32 q-rows
    const float csq  = rsqrtf((float)dk[0]) * 1.44269504088896f; // scale*log2(e)
    const float mfac = -1e9f * 1.44269504088896f;                // exp2 domain
    const bool use_mask = (maskflag[0] != 0);

    __shared__ __align__(16) _Float16 KT[2][TILE_HALFS];   // [buf][r*64 + d swz]
    __shared__ __align__(16) _Float16 VT[2][TILE_HALFS];   // [buf][d*64 + r swz]
    __shared__ __align__(16) _Float16 Pw[4][32][KPAD];     // per-wave P: [q][k]

    // ---- Q fragments (B-operand layout), pre-scaled; 2 frags of 16 rows ----
    half8 qf[2][2];
    #pragma unroll
    for (int f = 0; f < 2; ++f) {
        #pragma unroll
        for (int kc = 0; kc < 2; ++kc) {
            const float4* src = (const float4*)(Qh + (long)(q0 + f*16 + l15) * DHEAD + kc*32 + rq8);
            float4 a = src[0], b = src[1];
            union { pk16x2 p[4]; half8 h; } u;
            u.p[0] = __builtin_amdgcn_cvt_pkrtz(a.x*csq, a.y*csq);
            u.p[1] = __builtin_amdgcn_cvt_pkrtz(a.z*csq, a.w*csq);
            u.p[2] = __builtin_amdgcn_cvt_pkrtz(b.x*csq, b.y*csq);
            u.p[3] = __builtin_amdgcn_cvt_pkrtz(b.z*csq, b.w*csq);
            qf[f][kc] = u.h;
        }
    }

    // ---- async staging: 4x global_load_lds(16B) per thread per tile ----
    auto stage = [&](int kt, int b) {
        const _Float16* k8 = gk + (long)kt * TILE_HALFS + tid * 8;
        const _Float16* v8 = gv + (long)kt * TILE_HALFS + tid * 8;
        gl_lds16(k8,        &KT[b][tid * 8]);
        gl_lds16(k8 + 2048, &KT[b][2048 + tid * 8]);
        gl_lds16(v8,        &VT[b][tid * 8]);
        gl_lds16(v8 + 2048, &VT[b][2048 + tid * 8]);
    };

    f32x4 o[2][4];
    #pragma unroll
    for (int f = 0; f < 2; ++f)
        #pragma unroll
        for (int dt = 0; dt < 4; ++dt) o[f][dt] = (f32x4){0.f, 0.f, 0.f, 0.f};
    float m_i[2] = {-INFINITY, -INFINITY};
    float l_i[2] = {0.0f, 0.0f};

    stage(0, 0);
    __syncthreads();   // implicit vmcnt(0) drain before barrier

    for (int kt = 0; kt < NT; ++kt) {
        const int b = kt & 1;
        if (kt + 1 < NT) stage(kt + 1, b ^ 1);   // async prefetch overlaps compute

        // ---- S^T = K · Q^T for both frags (K-frag reads shared) ----
        f32x4 st[2][4];
        #pragma unroll
        for (int f = 0; f < 2; ++f)
            #pragma unroll
            for (int nt = 0; nt < 4; ++nt) st[f][nt] = (f32x4){0.f,0.f,0.f,0.f};
        __builtin_amdgcn_s_setprio(1);
        #pragma unroll
        for (int nt = 0; nt < 4; ++nt) {
            const int rb = (nt << 10) + (l15 << 6);
            #pragma unroll
            for (int kc = 0; kc < 2; ++kc) {
                half8 af = *(const half8*)&KT[b][rb + ((kc*32 + rq8) ^ sw)];
                st[0][nt] = __builtin_amdgcn_mfma_f32_16x16x32_f16(af, qf[0][kc], st[0][nt], 0, 0, 0);
                st[1][nt] = __builtin_amdgcn_mfma_f32_16x16x32_f16(af, qf[1][kc], st[1][nt], 0, 0, 0);
            }
        }
        __builtin_amdgcn_s_setprio(0);

        if (use_mask) {
            #pragma unroll
            for (int f = 0; f < 2; ++f) {
                const long mrow = (long)(q0 + f*16 + l15) * S_LEN + kt*BK;
                #pragma unroll
                for (int nt = 0; nt < 4; ++nt)
                    #pragma unroll
                    for (int r = 0; r < 4; ++r)
                        st[f][nt][r] += mfac * mask[mrow + nt*16 + quad*4 + r];
            }
        }

        // ---- online softmax (exp2 domain), exact defer-rescale ----
        #pragma unroll
        for (int f = 0; f < 2; ++f) {
            float mx = fmaxf(fmaxf(fmaxf(st[f][0][0], st[f][0][1]), fmaxf(st[f][0][2], st[f][0][3])),
                             fmaxf(fmaxf(st[f][1][0], st[f][1][1]), fmaxf(st[f][1][2], st[f][1][3])));
            float mx2 = fmaxf(fmaxf(fmaxf(st[f][2][0], st[f][2][1]), fmaxf(st[f][2][2], st[f][2][3])),
                              fmaxf(fmaxf(st[f][3][0], st[f][3][1]), fmaxf(st[f][3][2], st[f][3][3])));
            mx = fmaxf(mx, mx2);
            mx = fmaxf(mx, __shfl_xor(mx, 16, 64));
            mx = fmaxf(mx, __shfl_xor(mx, 32, 64));
            const bool need = __any(mx > m_i[f]);     // wave-uniform
            const float mnew = need ? fmaxf(m_i[f], mx) : m_i[f];
            float rsum = 0.0f;
            #pragma unroll
            for (int nt = 0; nt < 4; ++nt) {
                #pragma unroll
                for (int r = 0; r < 4; ++r) {
                    float p = __builtin_amdgcn_exp2f(st[f][nt][r] - mnew);
                    st[f][nt][r] = p;
                    rsum += p;
                }
            }
            rsum += __shfl_xor(rsum, 16, 64);
            rsum += __shfl_xor(rsum, 32, 64);
            if (need) {
                const float alpha = __builtin_amdgcn_exp2f(m_i[f] - mnew);
                #pragma unroll
                for (int r = 0; r < 4; ++r) {
                    float a_r = __shfl(alpha, quad*4 + r, 64);
                    #pragma unroll
                    for (int dt = 0; dt < 4; ++dt) o[f][dt][r] *= a_r;
                }
                l_i[f] = alpha * l_i[f] + rsum;
                m_i[f] = mnew;
            } else {
                l_i[f] += rsum;
            }
        }

        // ---- P -> per-wave LDS (b64 writes) ----
        #pragma unroll
        for (int f = 0; f < 2; ++f)
            #pragma unroll
            for (int nt = 0; nt < 4; ++nt) {
                union { pk16x2 p[2]; half4v h; } up;
                up.p[0] = __builtin_amdgcn_cvt_pkrtz(st[f][nt][0], st[f][nt][1]);
                up.p[1] = __builtin_amdgcn_cvt_pkrtz(st[f][nt][2], st[f][nt][3]);
                *(half4v*)&Pw[wave][f*16 + l15][nt*16 + quad*4] = up.h;
            }

        // ---- O += P·V  (V-frag reads shared across frags) ----
        __builtin_amdgcn_s_setprio(1);
        #pragma unroll
        for (int kc2 = 0; kc2 < 2; ++kc2) {
            half8 pa0 = *(const half8*)&Pw[wave][l15][kc2*32 + rq8];
            half8 pa1 = *(const half8*)&Pw[wave][16 + l15][kc2*32 + rq8];
            #pragma unroll
            for (int dt = 0; dt < 4; ++dt) {
                const int db = (dt << 10) + (l15 << 6);
                half8 vb = *(const half8*)&VT[b][db + ((kc2*32 + rq8) ^ sw)];
                o[0][dt] = __builtin_amdgcn_mfma_f32_16x16x32_f16(pa0, vb, o[0][dt], 0, 0, 0);
                o[1][dt] = __builtin_amdgcn_mfma_f32_16x16x32_f16(pa1, vb, o[1][dt], 0, 0, 0);
            }
        }
        __builtin_amdgcn_s_setprio(0);

        if (kt + 1 < NT) __syncthreads();   // one barrier per K-tile
    }

    // ---- epilogue: O /= l ----
    #pragma unroll
    for (int f = 0; f < 2; ++f) {
        #pragma unroll
        for (int r = 0; r < 4; ++r) {
            float lq = __shfl(l_i[f], quad*4 + r, 64);
            float linv = __builtin_amdgcn_rcpf(lq);
            const long row = (long)(q0 + f*16 + quad*4 + r) * DHEAD;
            #pragma unroll
            for (int dt = 0; dt < 4; ++dt)
                Oh[row + dt*16 + l15] = o[f][dt][r] * linv;
        }
    }
}

// ---------------------------------------------------------------------------
// Fallback (ws too small): previous verified kernel, verbatim.
// ---------------------------------------------------------------------------
__global__ __launch_bounds__(256, 2) void attn_kernel_fb(
    const float* __restrict__ Q, const float* __restrict__ K,
    const float* __restrict__ V, const int* __restrict__ dk,
    const float* __restrict__ mask, const int* __restrict__ maskflag,
    float* __restrict__ O)
{
    const int qt   = blockIdx.x;
    const int bh   = blockIdx.y;
    const int tid  = threadIdx.x;
    const int wave = tid >> 6;
    const int lane = tid & 63;
    const int l15  = lane & 15;
    const int quad = lane >> 4;

    const long base = (long)bh * S_LEN * DHEAD;
    const float* Qh = Q + base;
    const float* Kh = K + base;
    const float* Vh = V + base;
    float*       Oh = O + base;

    const int q0 = qt * BQ + wave * 32;
    const float csq  = rsqrtf((float)dk[0]) * 1.44269504088896f;
    const float mfac = -1e9f * 1.44269504088896f;
    const bool use_mask = (maskflag[0] != 0);

    __shared__ __align__(16) _Float16 Kt[2][BK][KPAD];
    __shared__ __align__(16) _Float16 Vt[2][DHEAD * KPAD];
    __shared__ __align__(16) _Float16 Pw[4][32][KPAD];

    half8 qf[2][2];
    #pragma unroll
    for (int f = 0; f < 2; ++f) {
        #pragma unroll
        for (int kc = 0; kc < 2; ++kc) {
            const float4* src = (const float4*)(Qh + (long)(q0 + f*16 + l15) * DHEAD + kc*32 + quad*8);
            float4 a = src[0], b = src[1];
            union { pk16x2 p[4]; half8 h; } u;
            u.p[0] = __builtin_amdgcn_cvt_pkrtz(a.x*csq, a.y*csq);
            u.p[1] = __builtin_amdgcn_cvt_pkrtz(a.z*csq, a.w*csq);
            u.p[2] = __builtin_amdgcn_cvt_pkrtz(b.x*csq, b.y*csq);
            u.p[3] = __builtin_amdgcn_cvt_pkrtz(b.z*csq, b.w*csq);
            qf[f][kc] = u.h;
        }
    }

    const int kr  = tid >> 2;
    const int ks  = tid & 3;
    const int vrp = tid >> 3;
    const int vdq = tid & 7;
    const float* Kb = Kh + (long)kr * DHEAD + ks * 16;
    const float* Vb = Vh + (long)(2 * vrp) * DHEAD + vdq * 8;
    const int vcol = (((vrp >> 2) ^ vdq) << 3) + ((2 * vrp) & 7);
    const int vd0  = vdq * 8;

    float4 kf[4], vf[4];
    auto load_tile = [&](int kt) {
        const float4* kp  = (const float4*)(Kb + (long)kt * BK * DHEAD);
        kf[0] = kp[0]; kf[1] = kp[1]; kf[2] = kp[2]; kf[3] = kp[3];
        const float4* vp0 = (const float4*)(Vb + (long)kt * BK * DHEAD);
        const float4* vp1 = (const float4*)(Vb + (long)kt * BK * DHEAD + DHEAD);
        vf[0] = vp0[0]; vf[1] = vp0[1]; vf[2] = vp1[0]; vf[3] = vp1[1];
    };
    auto store_tile = [&](int b) {
        union { pk16x2 p[4]; half8 h; } u0, u1;
        u0.p[0] = __builtin_amdgcn_cvt_pkrtz(kf[0].x, kf[0].y);
        u0.p[1] = __builtin_amdgcn_cvt_pkrtz(kf[0].z, kf[0].w);
        u0.p[2] = __builtin_amdgcn_cvt_pkrtz(kf[1].x, kf[1].y);
        u0.p[3] = __builtin_amdgcn_cvt_pkrtz(kf[1].z, kf[1].w);
        u1.p[0] = __builtin_amdgcn_cvt_pkrtz(kf[2].x, kf[2].y);
        u1.p[1] = __builtin_amdgcn_cvt_pkrtz(kf[2].z, kf[2].w);
        u1.p[2] = __builtin_amdgcn_cvt_pkrtz(kf[3].x, kf[3].y);
        u1.p[3] = __builtin_amdgcn_cvt_pkrtz(kf[3].z, kf[3].w);
        *(half8*)&Kt[b][kr][ks*16]     = u0.h;
        *(half8*)&Kt[b][kr][ks*16 + 8] = u1.h;
        _Float16* vt = &Vt[b][0];
        *(pk16x2*)&vt[(vd0+0)*KPAD + vcol] = __builtin_amdgcn_cvt_pkrtz(vf[0].x, vf[2].x);
        *(pk16x2*)&vt[(vd0+1)*KPAD + vcol] = __builtin_amdgcn_cvt_pkrtz(vf[0].y, vf[2].y);
        *(pk16x2*)&vt[(vd0+2)*KPAD + vcol] = __builtin_amdgcn_cvt_pkrtz(vf[0].z, vf[2].z);
        *(pk16x2*)&vt[(vd0+3)*KPAD + vcol] = __builtin_amdgcn_cvt_pkrtz(vf[0].w, vf[2].w);
        *(pk16x2*)&vt[(vd0+4)*KPAD + vcol] = __builtin_amdgcn_cvt_pkrtz(vf[1].x, vf[3].x);
        *(pk16x2*)&vt[(vd0+5)*KPAD + vcol] = __builtin_amdgcn_cvt_pkrtz(vf[1].y, vf[3].y);
        *(pk16x2*)&vt[(vd0+6)*KPAD + vcol] = __builtin_amdgcn_cvt_pkrtz(vf[1].z, vf[3].z);
        *(pk16x2*)&vt[(vd0+7)*KPAD + vcol] = __builtin_amdgcn_cvt_pkrtz(vf[1].w, vf[3].w);
    };

    f32x4 o[2][4];
    #pragma unroll
    for (int f = 0; f < 2; ++f)
        #pragma unroll
        for (int dt = 0; dt < 4; ++dt) o[f][dt] = (f32x4){0.f, 0.f, 0.f, 0.f};
    float m_i[2] = {-INFINITY, -INFINITY};
    float l_i[2] = {0.0f, 0.0f};

    load_tile(0);
    store_tile(0);
    __syncthreads();

    for (int kt = 0; kt < NT; ++kt) {
        const int b = kt & 1;
        if (kt + 1 < NT) load_tile(kt + 1);

        f32x4 st[2][4];
        #pragma unroll
        for (int f = 0; f < 2; ++f)
            #pragma unroll
            for (int nt = 0; nt < 4; ++nt) st[f][nt] = (f32x4){0.f,0.f,0.f,0.f};
        #pragma unroll
        for (int nt = 0; nt < 4; ++nt) {
            #pragma unroll
            for (int kc = 0; kc < 2; ++kc) {
                half8 af = *(const half8*)&Kt[b][nt*16 + l15][kc*32 + quad*8];
                st[0][nt] = __builtin_amdgcn_mfma_f32_16x16x32_f16(af, qf[0][kc], st[0][nt], 0, 0, 0);
                st[1][nt] = __builtin_amdgcn_mfma_f32_16x16x32_f16(af, qf[1][kc], st[1][nt], 0, 0, 0);
            }
        }

        if (use_mask) {
            #pragma unroll
            for (int f = 0; f < 2; ++f) {
                const long mrow = (long)(q0 + f*16 + l15) * S_LEN + kt*BK;
                #pragma unroll
                for (int nt = 0; nt < 4; ++nt)
                    #pragma unroll
                    for (int r = 0; r < 4; ++r)
                        st[f][nt][r] += mfac * mask[mrow + nt*16 + quad*4 + r];
            }
        }

        float alpha[2];
        #pragma unroll
        for (int f = 0; f < 2; ++f) {
            float mx = fmaxf(fmaxf(fmaxf(st[f][0][0], st[f][0][1]), fmaxf(st[f][0][2], st[f][0][3])),
                             fmaxf(fmaxf(st[f][1][0], st[f][1][1]), fmaxf(st[f][1][2], st[f][1][3])));
            float mx2 = fmaxf(fmaxf(fmaxf(st[f][2][0], st[f][2][1]), fmaxf(st[f][2][2], st[f][2][3])),
                              fmaxf(fmaxf(st[f][3][0], st[f][3][1]), fmaxf(st[f][3][2], st[f][3][3])));
            mx = fmaxf(mx, mx2);
            mx = fmaxf(mx, __shfl_xor(mx, 16, 64));
            mx = fmaxf(mx, __shfl_xor(mx, 32, 64));
            float mnew = fmaxf(m_i[f], mx);
            float rsum = 0.0f;
            #pragma unroll
            for (int nt = 0; nt < 4; ++nt) {
                #pragma unroll
                for (int r = 0; r < 4; ++r) {
                    float p = __builtin_amdgcn_exp2f(st[f][nt][r] - mnew);
                    st[f][nt][r] = p;
                    rsum += p;
                }
            }
            rsum += __shfl_xor(rsum, 16, 64);
            rsum += __shfl_xor(rsum, 32, 64);
            alpha[f] = __builtin_amdgcn_exp2f(m_i[f] - mnew);
            l_i[f] = alpha[f] * l_i[f] + rsum;
            m_i[f] = mnew;
        }

        #pragma unroll
        for (int f = 0; f < 2; ++f)
            #pragma unroll
            for (int r = 0; r < 4; ++r) {
                float a_r = __shfl(alpha[f], quad*4 + r, 64);
                #pragma unroll
                for (int dt = 0; dt < 4; ++dt) o[f][dt][r] *= a_r;
            }

        #pragma unroll
        for (int f = 0; f < 2; ++f)
            #pragma unroll
            for (int nt = 0; nt < 4; ++nt) {
                union { pk16x2 p[2]; half4v h; } up;
                up.p[0] = __builtin_amdgcn_cvt_pkrtz(st[f][nt][0], st[f][nt][1]);
                up.p[1] = __builtin_amdgcn_cvt_pkrtz(st[f][nt][2], st[f][nt][3]);
                *(half4v*)&Pw[wave][f*16 + l15][nt*16 + quad*4] = up.h;
            }

        #pragma unroll
        for (int kc2 = 0; kc2 < 2; ++kc2) {
            half8 pa0 = *(const half8*)&Pw[wave][l15][kc2*32 + quad*8];
            half8 pa1 = *(const half8*)&Pw[wave][16 + l15][kc2*32 + quad*8];
            #pragma unroll
            for (int dt = 0; dt < 4; ++dt) {
                const int row = dt*16 + l15;
                const int pb  = (4*kc2 + quad) ^ (row >> 3);
                half8 vb = *(const half8*)&Vt[b][row*KPAD + pb*8];
                o[0][dt] = __builtin_amdgcn_mfma_f32_16x16x32_f16(pa0, vb, o[0][dt], 0, 0, 0);
                o[1][dt] = __builtin_amdgcn_mfma_f32_16x16x32_f16(pa1, vb, o[1][dt], 0, 0, 0);
            }
        }

        if (kt + 1 < NT) {
            store_tile((kt + 1) & 1);
            __syncthreads();
        }
    }

    #pragma unroll
    for (int f = 0; f < 2; ++f) {
        #pragma unroll
        for (int r = 0; r < 4; ++r) {
            float lq = __shfl(l_i[f], quad*4 + r, 64);
            float linv = __builtin_amdgcn_rcpf(lq);
            const long row = (long)(q0 + f*16 + quad*4 + r) * DHEAD;
            #pragma unroll
            for (int dt = 0; dt < 4; ++dt)
                Oh[row + dt*16 + l15] = o[f][dt][r] * linv;
        }
    }
}

extern "C" void kernel_launch(void* const* d_in, const int* in_sizes, int n_in,
                              void* d_out, int out_size, void* d_ws, size_t ws_size,
                              hipStream_t stream) {
    const float* Q    = (const float*)d_in[0];
    const float* K    = (const float*)d_in[1];
    const float* V    = (const float*)d_in[2];
    const int*   dk   = (const int*)d_in[3];
    const float* mask = (const float*)d_in[4];
    float* out = (float*)d_out;
    int* flag = (int*)d_ws;

    (void)hipMemsetAsync(flag, 0, sizeof(int), stream);

    const size_t WS_NEED = 256 + 2 * WS_KV_HALFS * sizeof(_Float16);  // ~16.8 MB
    dim3 grid(S_LEN / BQ, NBH);   // 32 q-tiles x (B*H) = 512 blocks

    if (ws_size >= WS_NEED) {
        _Float16* wsK = (_Float16*)((char*)d_ws + 256);
        _Float16* wsV = wsK + WS_KV_HALFS;
        conv_kernel<<<dim3(NBH * NT, 3), 256, 0, stream>>>(K, V, mask, wsK, wsV, flag);
        attn_ws_kernel<<<grid, 256, 0, stream>>>(Q, wsK, wsV, dk, mask, flag, out);
    } else {
        mask_flag_kernel<<<2048, 256, 0, stream>>>((const float4*)mask, flag);
        attn_kernel_fb<<<grid, 256, 0, stream>>>(Q, K, V, dk, mask, flag, out);
    }
}

// Round 2
// 263.653 us; speedup vs baseline: 1.0445x; 1.0445x over previous
//
#include <hip/hip_runtime.h>

#define S_LEN 4096
#define DHEAD 64
#define BQ    128      // fallback kernel: Q rows per block
#define BK    64       // K/V rows per tile
#define NT    (S_LEN / BK)
#define KPAD  72       // halfs; fallback P scratch row stride
#define NBH   16
#define TILE_HALFS (BK * DHEAD)   // 4096 halfs = 8 KB per tile image
#define WS_KV_HALFS ((size_t)NBH * NT * TILE_HALFS)

typedef __fp16   pk16x2 __attribute__((ext_vector_type(2)));  // cvt_pkrtz result
typedef _Float16 half4v __attribute__((ext_vector_type(4)));
typedef _Float16 half8  __attribute__((ext_vector_type(8)));
typedef float    f32x4  __attribute__((ext_vector_type(4)));

// async global->LDS, 16B per lane; LDS dest is wave-uniform base + lane*16
__device__ __forceinline__ void gl_lds16(const _Float16* g, _Float16* l) {
    __builtin_amdgcn_global_load_lds(
        (const __attribute__((address_space(1))) unsigned int*)g,
        (__attribute__((address_space(3))) unsigned int*)l, 16, 0, 0);
}

// ---------------------------------------------------------------------------
// Pass 1 (fallback path only): is the mask anywhere nonzero?
// ---------------------------------------------------------------------------
__global__ void mask_flag_kernel(const float4* __restrict__ mask, int* __restrict__ flag) {
    const long stride = 2048L * 256;
    long i = (long)blockIdx.x * 256 + threadIdx.x;
    int nz = 0;
    #pragma unroll
    for (int it = 0; it < 8; ++it) {
        float4 a = mask[i + it * stride];
        nz |= (a.x != 0.f) | (a.y != 0.f) | (a.z != 0.f) | (a.w != 0.f);
    }
    if (__any(nz)) {
        if ((threadIdx.x & 63) == 0) atomicOr(flag, 1);
    }
}

// ---------------------------------------------------------------------------
// Pass 1 (workspace path): convert K/V fp32 -> fp16 tile images in the exact
// swizzled LDS layout the attention kernel wants, AND scan the mask.
//   wsK tile image: [r][16B-chunk c] = K[r][8*(c ^ (r&7)) .. +8]   (row-major)
//   wsV tile image: [d][16B-chunk c] = V[8*(c ^ (d&7)) .. +8][d]   (transposed)
// grid = (1024, 3): y==0 K-tiles, y==1 V-tiles, y==2 mask scan.
// ---------------------------------------------------------------------------
__global__ void conv_kernel(const float* __restrict__ Kg, const float* __restrict__ Vg,
                            const float* __restrict__ mask,
                            _Float16* __restrict__ wsK, _Float16* __restrict__ wsV,
                            int* __restrict__ flag) {
    const int tid  = threadIdx.x;
    const int tile = blockIdx.x;                // 0..1023 = bh*64 + kt
    __shared__ __align__(16) _Float16 T[64][64];

    if (blockIdx.y == 0) {
        // ---- K: within-row 16B chunk permutation, rows stay row-major ----
        const float* Ksrc = Kg + (long)tile * TILE_HALFS;   // 4096 floats/tile
        _Float16*    dst  = wsK + (long)tile * TILE_HALFS;
        #pragma unroll
        for (int it = 0; it < 2; ++it) {
            int m = tid + it * 256;             // out chunk id 0..511
            int r = m >> 3, c = m & 7;
            const float4* s4 = (const float4*)(Ksrc + r * DHEAD + ((c ^ (r & 7)) << 3));
            float4 a = s4[0], b = s4[1];
            union { pk16x2 p[4]; half8 h; } u;
            u.p[0] = __builtin_amdgcn_cvt_pkrtz(a.x, a.y);
            u.p[1] = __builtin_amdgcn_cvt_pkrtz(a.z, a.w);
            u.p[2] = __builtin_amdgcn_cvt_pkrtz(b.x, b.y);
            u.p[3] = __builtin_amdgcn_cvt_pkrtz(b.z, b.w);
            *(half8*)(dst + m * 8) = u.h;
        }
    } else if (blockIdx.y == 1) {
        // ---- V: transpose 64x64 tile via LDS, then swizzled chunk writeout ----
        const float* Vsrc = Vg + (long)tile * TILE_HALFS;
        const int r  = tid >> 2;
        const int d0 = (tid & 3) << 4;
        const float4* s4 = (const float4*)(Vsrc + r * DHEAD + d0);
        float vv[16];
        *(float4*)&vv[0]  = s4[0];
        *(float4*)&vv[4]  = s4[1];
        *(float4*)&vv[8]  = s4[2];
        *(float4*)&vv[12] = s4[3];
        #pragma unroll
        for (int j = 0; j < 16; j += 2) {
            pk16x2 p = __builtin_amdgcn_cvt_pkrtz(vv[j], vv[j + 1]);
            T[d0 + j][r]     = *((_Float16*)&p);
            T[d0 + j + 1][r] = *((_Float16*)&p + 1);
        }
        __syncthreads();
        _Float16* dst = wsV + (long)tile * TILE_HALFS;
        #pragma unroll
        for (int it = 0; it < 2; ++it) {
            int m = tid + it * 256;
            int d = m >> 3, c = m & 7;
            *(half8*)(dst + m * 8) = *(const half8*)&T[d][(c ^ (d & 7)) << 3];
        }
    } else {
        // ---- mask scan: 1024 blocks x 256 threads x 16 float4 = 64 MB ----
        const float4* m4 = (const float4*)mask;
        const long stride = 1024L * 256;
        long i = (long)blockIdx.x * 256 + tid;
        int nz = 0;
        #pragma unroll
        for (int it = 0; it < 16; ++it) {
            float4 a = m4[i + it * stride];
            nz |= (a.x != 0.f) | (a.y != 0.f) | (a.z != 0.f) | (a.w != 0.f);
        }
        if (__any(nz)) {
            if ((tid & 63) == 0) atomicOr(flag, 1);
        }
    }
}

// ---------------------------------------------------------------------------
// Pass 2 (workspace path): flash attention, BQ=64 (one 16-row fragment per
// wave). grid = 1024 blocks -> 4 blocks/CU (LDS = 40960 B exactly fits 4x).
// K/V staged from fp16 tile images via global_load_lds; XOR-swizzled rows ->
// conflict-free ds_read_b128; P buffer unpadded [16][64] with same swizzle.
// ---------------------------------------------------------------------------
__global__ __launch_bounds__(256, 4) void attn_ws_kernel(
    const float* __restrict__ Q, const _Float16* __restrict__ KW,
    const _Float16* __restrict__ VW, const int* __restrict__ dk,
    const float* __restrict__ mask, const int* __restrict__ maskflag,
    float* __restrict__ O)
{
    const int qt   = blockIdx.x;      // 0..63
    const int bh   = blockIdx.y;      // 0..15
    const int tid  = threadIdx.x;
    const int wave = tid >> 6;
    const int lane = tid & 63;
    const int l15  = lane & 15;
    const int quad = lane >> 4;
    const int sw   = (l15 & 7) << 3;  // row-XOR swizzle (halfs); rows 16-periodic
    const int rq8  = quad << 3;

    const long base = (long)bh * S_LEN * DHEAD;
    const float* Qh = Q + base;
    float*       Oh = O + base;
    const _Float16* gk = KW + (long)bh * (NT * TILE_HALFS);
    const _Float16* gv = VW + (long)bh * (NT * TILE_HALFS);

    const int q0 = qt * 64 + wave * 16;            // this wave's 16 q-rows
    const float csq  = rsqrtf((float)dk[0]) * 1.44269504088896f; // scale*log2(e)
    const float mfac = -1e9f * 1.44269504088896f;                // exp2 domain
    const bool use_mask = (maskflag[0] != 0);

    __shared__ __align__(16) _Float16 KT[2][TILE_HALFS];   // 16384 B
    __shared__ __align__(16) _Float16 VT[2][TILE_HALFS];   // 16384 B
    __shared__ __align__(16) _Float16 Pw[4][16][64];       //  8192 B (swizzled)

    // ---- Q fragment (B-operand layout), pre-scaled; 16 rows ----
    half8 qf[2];
    #pragma unroll
    for (int kc = 0; kc < 2; ++kc) {
        const float4* src = (const float4*)(Qh + (long)(q0 + l15) * DHEAD + kc*32 + rq8);
        float4 a = src[0], b = src[1];
        union { pk16x2 p[4]; half8 h; } u;
        u.p[0] = __builtin_amdgcn_cvt_pkrtz(a.x*csq, a.y*csq);
        u.p[1] = __builtin_amdgcn_cvt_pkrtz(a.z*csq, a.w*csq);
        u.p[2] = __builtin_amdgcn_cvt_pkrtz(b.x*csq, b.y*csq);
        u.p[3] = __builtin_amdgcn_cvt_pkrtz(b.z*csq, b.w*csq);
        qf[kc] = u.h;
    }

    // ---- async staging: 4x global_load_lds(16B) per thread per tile ----
    auto stage = [&](int kt, int b) {
        const _Float16* k8 = gk + (long)kt * TILE_HALFS + tid * 8;
        const _Float16* v8 = gv + (long)kt * TILE_HALFS + tid * 8;
        gl_lds16(k8,        &KT[b][tid * 8]);
        gl_lds16(k8 + 2048, &KT[b][2048 + tid * 8]);
        gl_lds16(v8,        &VT[b][tid * 8]);
        gl_lds16(v8 + 2048, &VT[b][2048 + tid * 8]);
    };

    f32x4 o[4];
    #pragma unroll
    for (int dt = 0; dt < 4; ++dt) o[dt] = (f32x4){0.f, 0.f, 0.f, 0.f};
    float m_i = -INFINITY;
    float l_i = 0.0f;

    stage(0, 0);
    __syncthreads();   // implicit vmcnt(0) drain before barrier

    for (int kt = 0; kt < NT; ++kt) {
        const int b = kt & 1;
        if (kt + 1 < NT) stage(kt + 1, b ^ 1);   // async prefetch overlaps compute

        // ---- S^T = K · Q^T ----
        f32x4 st[4];
        #pragma unroll
        for (int nt = 0; nt < 4; ++nt) st[nt] = (f32x4){0.f,0.f,0.f,0.f};
        __builtin_amdgcn_s_setprio(1);
        #pragma unroll
        for (int nt = 0; nt < 4; ++nt) {
            const int rb = (nt << 10) + (l15 << 6);
            #pragma unroll
            for (int kc = 0; kc < 2; ++kc) {
                half8 af = *(const half8*)&KT[b][rb + ((kc*32 + rq8) ^ sw)];
                st[nt] = __builtin_amdgcn_mfma_f32_16x16x32_f16(af, qf[kc], st[nt], 0, 0, 0);
            }
        }
        __builtin_amdgcn_s_setprio(0);

        if (use_mask) {
            const long mrow = (long)(q0 + l15) * S_LEN + kt*BK;
            #pragma unroll
            for (int nt = 0; nt < 4; ++nt)
                #pragma unroll
                for (int r = 0; r < 4; ++r)
                    st[nt][r] += mfac * mask[mrow + nt*16 + quad*4 + r];
        }

        // ---- online softmax (exp2 domain), exact defer-rescale ----
        {
            float mx = fmaxf(fmaxf(fmaxf(st[0][0], st[0][1]), fmaxf(st[0][2], st[0][3])),
                             fmaxf(fmaxf(st[1][0], st[1][1]), fmaxf(st[1][2], st[1][3])));
            float mx2 = fmaxf(fmaxf(fmaxf(st[2][0], st[2][1]), fmaxf(st[2][2], st[2][3])),
                              fmaxf(fmaxf(st[3][0], st[3][1]), fmaxf(st[3][2], st[3][3])));
            mx = fmaxf(mx, mx2);
            mx = fmaxf(mx, __shfl_xor(mx, 16, 64));
            mx = fmaxf(mx, __shfl_xor(mx, 32, 64));
            const bool need = __any(mx > m_i);     // wave-uniform
            const float mnew = need ? fmaxf(m_i, mx) : m_i;
            float rsum = 0.0f;
            #pragma unroll
            for (int nt = 0; nt < 4; ++nt) {
                #pragma unroll
                for (int r = 0; r < 4; ++r) {
                    float p = __builtin_amdgcn_exp2f(st[nt][r] - mnew);
                    st[nt][r] = p;
                    rsum += p;
                }
            }
            rsum += __shfl_xor(rsum, 16, 64);
            rsum += __shfl_xor(rsum, 32, 64);
            if (need) {
                const float alpha = __builtin_amdgcn_exp2f(m_i - mnew);
                #pragma unroll
                for (int r = 0; r < 4; ++r) {
                    float a_r = __shfl(alpha, quad*4 + r, 64);
                    #pragma unroll
                    for (int dt = 0; dt < 4; ++dt) o[dt][r] *= a_r;
                }
                l_i = alpha * l_i + rsum;
                m_i = mnew;
            } else {
                l_i += rsum;
            }
        }

        // ---- P -> per-wave LDS (b64 writes, XOR-swizzled; 2-way max) ----
        #pragma unroll
        for (int nt = 0; nt < 4; ++nt) {
            union { pk16x2 p[2]; half4v h; } up;
            up.p[0] = __builtin_amdgcn_cvt_pkrtz(st[nt][0], st[nt][1]);
            up.p[1] = __builtin_amdgcn_cvt_pkrtz(st[nt][2], st[nt][3]);
            *(half4v*)&Pw[wave][l15][(nt*16 + quad*4) ^ sw] = up.h;
        }

        // ---- O += P·V ----
        __builtin_amdgcn_s_setprio(1);
        #pragma unroll
        for (int kc2 = 0; kc2 < 2; ++kc2) {
            half8 pa = *(const half8*)&Pw[wave][l15][(kc2*32 + rq8) ^ sw];
            #pragma unroll
            for (int dt = 0; dt < 4; ++dt) {
                const int db = (dt << 10) + (l15 << 6);
                half8 vb = *(const half8*)&VT[b][db + ((kc2*32 + rq8) ^ sw)];
                o[dt] = __builtin_amdgcn_mfma_f32_16x16x32_f16(pa, vb, o[dt], 0, 0, 0);
            }
        }
        __builtin_amdgcn_s_setprio(0);

        if (kt + 1 < NT) __syncthreads();   // one barrier per K-tile
    }

    // ---- epilogue: O /= l ----
    #pragma unroll
    for (int r = 0; r < 4; ++r) {
        float lq = __shfl(l_i, quad*4 + r, 64);
        float linv = __builtin_amdgcn_rcpf(lq);
        const long row = (long)(q0 + quad*4 + r) * DHEAD;
        #pragma unroll
        for (int dt = 0; dt < 4; ++dt)
            Oh[row + dt*16 + l15] = o[dt][r] * linv;
    }
}

// ---------------------------------------------------------------------------
// Fallback (ws too small): previously verified kernel, verbatim.
// ---------------------------------------------------------------------------
__global__ __launch_bounds__(256, 2) void attn_kernel_fb(
    const float* __restrict__ Q, const float* __restrict__ K,
    const float* __restrict__ V, const int* __restrict__ dk,
    const float* __restrict__ mask, const int* __restrict__ maskflag,
    float* __restrict__ O)
{
    const int qt   = blockIdx.x;
    const int bh   = blockIdx.y;
    const int tid  = threadIdx.x;
    const int wave = tid >> 6;
    const int lane = tid & 63;
    const int l15  = lane & 15;
    const int quad = lane >> 4;

    const long base = (long)bh * S_LEN * DHEAD;
    const float* Qh = Q + base;
    const float* Kh = K + base;
    const float* Vh = V + base;
    float*       Oh = O + base;

    const int q0 = qt * BQ + wave * 32;
    const float csq  = rsqrtf((float)dk[0]) * 1.44269504088896f;
    const float mfac = -1e9f * 1.44269504088896f;
    const bool use_mask = (maskflag[0] != 0);

    __shared__ __align__(16) _Float16 Kt[2][BK][KPAD];
    __shared__ __align__(16) _Float16 Vt[2][DHEAD * KPAD];
    __shared__ __align__(16) _Float16 Pw[4][32][KPAD];

    half8 qf[2][2];
    #pragma unroll
    for (int f = 0; f < 2; ++f) {
        #pragma unroll
        for (int kc = 0; kc < 2; ++kc) {
            const float4* src = (const float4*)(Qh + (long)(q0 + f*16 + l15) * DHEAD + kc*32 + quad*8);
            float4 a = src[0], b = src[1];
            union { pk16x2 p[4]; half8 h; } u;
            u.p[0] = __builtin_amdgcn_cvt_pkrtz(a.x*csq, a.y*csq);
            u.p[1] = __builtin_amdgcn_cvt_pkrtz(a.z*csq, a.w*csq);
            u.p[2] = __builtin_amdgcn_cvt_pkrtz(b.x*csq, b.y*csq);
            u.p[3] = __builtin_amdgcn_cvt_pkrtz(b.z*csq, b.w*csq);
            qf[f][kc] = u.h;
        }
    }

    const int kr  = tid >> 2;
    const int ks  = tid & 3;
    const int vrp = tid >> 3;
    const int vdq = tid & 7;
    const float* Kb = Kh + (long)kr * DHEAD + ks * 16;
    const float* Vb = Vh + (long)(2 * vrp) * DHEAD + vdq * 8;
    const int vcol = (((vrp >> 2) ^ vdq) << 3) + ((2 * vrp) & 7);
    const int vd0  = vdq * 8;

    float4 kf[4], vf[4];
    auto load_tile = [&](int kt) {
        const float4* kp  = (const float4*)(Kb + (long)kt * BK * DHEAD);
        kf[0] = kp[0]; kf[1] = kp[1]; kf[2] = kp[2]; kf[3] = kp[3];
        const float4* vp0 = (const float4*)(Vb + (long)kt * BK * DHEAD);
        const float4* vp1 = (const float4*)(Vb + (long)kt * BK * DHEAD + DHEAD);
        vf[0] = vp0[0]; vf[1] = vp0[1]; vf[2] = vp1[0]; vf[3] = vp1[1];
    };
    auto store_tile = [&](int b) {
        union { pk16x2 p[4]; half8 h; } u0, u1;
        u0.p[0] = __builtin_amdgcn_cvt_pkrtz(kf[0].x, kf[0].y);
        u0.p[1] = __builtin_amdgcn_cvt_pkrtz(kf[0].z, kf[0].w);
        u0.p[2] = __builtin_amdgcn_cvt_pkrtz(kf[1].x, kf[1].y);
        u0.p[3] = __builtin_amdgcn_cvt_pkrtz(kf[1].z, kf[1].w);
        u1.p[0] = __builtin_amdgcn_cvt_pkrtz(kf[2].x, kf[2].y);
        u1.p[1] = __builtin_amdgcn_cvt_pkrtz(kf[2].z, kf[2].w);
        u1.p[2] = __builtin_amdgcn_cvt_pkrtz(kf[3].x, kf[3].y);
        u1.p[3] = __builtin_amdgcn_cvt_pkrtz(kf[3].z, kf[3].w);
        *(half8*)&Kt[b][kr][ks*16]     = u0.h;
        *(half8*)&Kt[b][kr][ks*16 + 8] = u1.h;
        _Float16* vt = &Vt[b][0];
        *(pk16x2*)&vt[(vd0+0)*KPAD + vcol] = __builtin_amdgcn_cvt_pkrtz(vf[0].x, vf[2].x);
        *(pk16x2*)&vt[(vd0+1)*KPAD + vcol] = __builtin_amdgcn_cvt_pkrtz(vf[0].y, vf[2].y);
        *(pk16x2*)&vt[(vd0+2)*KPAD + vcol] = __builtin_amdgcn_cvt_pkrtz(vf[0].z, vf[2].z);
        *(pk16x2*)&vt[(vd0+3)*KPAD + vcol] = __builtin_amdgcn_cvt_pkrtz(vf[0].w, vf[2].w);
        *(pk16x2*)&vt[(vd0+4)*KPAD + vcol] = __builtin_amdgcn_cvt_pkrtz(vf[1].x, vf[3].x);
        *(pk16x2*)&vt[(vd0+5)*KPAD + vcol] = __builtin_amdgcn_cvt_pkrtz(vf[1].y, vf[3].y);
        *(pk16x2*)&vt[(vd0+6)*KPAD + vcol] = __builtin_amdgcn_cvt_pkrtz(vf[1].z, vf[3].z);
        *(pk16x2*)&vt[(vd0+7)*KPAD + vcol] = __builtin_amdgcn_cvt_pkrtz(vf[1].w, vf[3].w);
    };

    f32x4 o[2][4];
    #pragma unroll
    for (int f = 0; f < 2; ++f)
        #pragma unroll
        for (int dt = 0; dt < 4; ++dt) o[f][dt] = (f32x4){0.f, 0.f, 0.f, 0.f};
    float m_i[2] = {-INFINITY, -INFINITY};
    float l_i[2] = {0.0f, 0.0f};

    load_tile(0);
    store_tile(0);
    __syncthreads();

    for (int kt = 0; kt < NT; ++kt) {
        const int b = kt & 1;
        if (kt + 1 < NT) load_tile(kt + 1);

        f32x4 st[2][4];
        #pragma unroll
        for (int f = 0; f < 2; ++f)
            #pragma unroll
            for (int nt = 0; nt < 4; ++nt) st[f][nt] = (f32x4){0.f,0.f,0.f,0.f};
        #pragma unroll
        for (int nt = 0; nt < 4; ++nt) {
            #pragma unroll
            for (int kc = 0; kc < 2; ++kc) {
                half8 af = *(const half8*)&Kt[b][nt*16 + l15][kc*32 + quad*8];
                st[0][nt] = __builtin_amdgcn_mfma_f32_16x16x32_f16(af, qf[0][kc], st[0][nt], 0, 0, 0);
                st[1][nt] = __builtin_amdgcn_mfma_f32_16x16x32_f16(af, qf[1][kc], st[1][nt], 0, 0, 0);
            }
        }

        if (use_mask) {
            #pragma unroll
            for (int f = 0; f < 2; ++f) {
                const long mrow = (long)(q0 + f*16 + l15) * S_LEN + kt*BK;
                #pragma unroll
                for (int nt = 0; nt < 4; ++nt)
                    #pragma unroll
                    for (int r = 0; r < 4; ++r)
                        st[f][nt][r] += mfac * mask[mrow + nt*16 + quad*4 + r];
            }
        }

        float alpha[2];
        #pragma unroll
        for (int f = 0; f < 2; ++f) {
            float mx = fmaxf(fmaxf(fmaxf(st[f][0][0], st[f][0][1]), fmaxf(st[f][0][2], st[f][0][3])),
                             fmaxf(fmaxf(st[f][1][0], st[f][1][1]), fmaxf(st[f][1][2], st[f][1][3])));
            float mx2 = fmaxf(fmaxf(fmaxf(st[f][2][0], st[f][2][1]), fmaxf(st[f][2][2], st[f][2][3])),
                              fmaxf(fmaxf(st[f][3][0], st[f][3][1]), fmaxf(st[f][3][2], st[f][3][3])));
            mx = fmaxf(mx, mx2);
            mx = fmaxf(mx, __shfl_xor(mx, 16, 64));
            mx = fmaxf(mx, __shfl_xor(mx, 32, 64));
            float mnew = fmaxf(m_i[f], mx);
            float rsum = 0.0f;
            #pragma unroll
            for (int nt = 0; nt < 4; ++nt) {
                #pragma unroll
                for (int r = 0; r < 4; ++r) {
                    float p = __builtin_amdgcn_exp2f(st[f][nt][r] - mnew);
                    st[f][nt][r] = p;
                    rsum += p;
                }
            }
            rsum += __shfl_xor(rsum, 16, 64);
            rsum += __shfl_xor(rsum, 32, 64);
            alpha[f] = __builtin_amdgcn_exp2f(m_i[f] - mnew);
            l_i[f] = alpha[f] * l_i[f] + rsum;
            m_i[f] = mnew;
        }

        #pragma unroll
        for (int f = 0; f < 2; ++f)
            #pragma unroll
            for (int r = 0; r < 4; ++r) {
                float a_r = __shfl(alpha[f], quad*4 + r, 64);
                #pragma unroll
                for (int dt = 0; dt < 4; ++dt) o[f][dt][r] *= a_r;
            }

        #pragma unroll
        for (int f = 0; f < 2; ++f)
            #pragma unroll
            for (int nt = 0; nt < 4; ++nt) {
                union { pk16x2 p[2]; half4v h; } up;
                up.p[0] = __builtin_amdgcn_cvt_pkrtz(st[f][nt][0], st[f][nt][1]);
                up.p[1] = __builtin_amdgcn_cvt_pkrtz(st[f][nt][2], st[f][nt][3]);
                *(half4v*)&Pw[wave][f*16 + l15][nt*16 + quad*4] = up.h;
            }

        #pragma unroll
        for (int kc2 = 0; kc2 < 2; ++kc2) {
            half8 pa0 = *(const half8*)&Pw[wave][l15][kc2*32 + quad*8];
            half8 pa1 = *(const half8*)&Pw[wave][16 + l15][kc2*32 + quad*8];
            #pragma unroll
            for (int dt = 0; dt < 4; ++dt) {
                const int row = dt*16 + l15;
                const int pb  = (4*kc2 + quad) ^ (row >> 3);
                half8 vb = *(const half8*)&Vt[b][row*KPAD + pb*8];
                o[0][dt] = __builtin_amdgcn_mfma_f32_16x16x32_f16(pa0, vb, o[0][dt], 0, 0, 0);
                o[1][dt] = __builtin_amdgcn_mfma_f32_16x16x32_f16(pa1, vb, o[1][dt], 0, 0, 0);
            }
        }

        if (kt + 1 < NT) {
            store_tile((kt + 1) & 1);
            __syncthreads();
        }
    }

    #pragma unroll
    for (int f = 0; f < 2; ++f) {
        #pragma unroll
        for (int r = 0; r < 4; ++r) {
            float lq = __shfl(l_i[f], quad*4 + r, 64);
            float linv = __builtin_amdgcn_rcpf(lq);
            const long row = (long)(q0 + f*16 + quad*4 + r) * DHEAD;
            #pragma unroll
            for (int dt = 0; dt < 4; ++dt)
                Oh[row + dt*16 + l15] = o[f][dt][r] * linv;
        }
    }
}

extern "C" void kernel_launch(void* const* d_in, const int* in_sizes, int n_in,
                              void* d_out, int out_size, void* d_ws, size_t ws_size,
                              hipStream_t stream) {
    const float* Q    = (const float*)d_in[0];
    const float* K    = (const float*)d_in[1];
    const float* V    = (const float*)d_in[2];
    const int*   dk   = (const int*)d_in[3];
    const float* mask = (const float*)d_in[4];
    float* out = (float*)d_out;
    int* flag = (int*)d_ws;

    (void)hipMemsetAsync(flag, 0, sizeof(int), stream);

    const size_t WS_NEED = 256 + 2 * WS_KV_HALFS * sizeof(_Float16);  // ~16.8 MB

    if (ws_size >= WS_NEED) {
        _Float16* wsK = (_Float16*)((char*)d_ws + 256);
        _Float16* wsV = wsK + WS_KV_HALFS;
        conv_kernel<<<dim3(NBH * NT, 3), 256, 0, stream>>>(K, V, mask, wsK, wsV, flag);
        dim3 grid(S_LEN / 64, NBH);   // 64 q-tiles x 16 bh = 1024 blocks (4/CU)
        attn_ws_kernel<<<grid, 256, 0, stream>>>(Q, wsK, wsV, dk, mask, flag, out);
    } else {
        mask_flag_kernel<<<2048, 256, 0, stream>>>((const float4*)mask, flag);
        dim3 grid(S_LEN / BQ, NBH);   // 32 q-tiles x 16 bh = 512 blocks
        attn_kernel_fb<<<grid, 256, 0, stream>>>(Q, K, V, dk, mask, flag, out);
    }
}